// Round 2
// baseline (661.644 us; speedup 1.0000x reference)
//
#include <hip/hip_runtime.h>
#include <hip/hip_bf16.h>

// GlobalAttention (general): B=32, T=512, S=1024, D=1024, f32 in/out.
// Split-bf16 (hi+lo) MFMA GEMMs; 8-phase 256x256 tile schedule (T3+T4+T5):
// BK=32, 4 planes/K-tile (Ah,Al,Bh,Bl), 2x double-buffered LDS (128KB),
// counted vmcnt (never drained in steady state), setprio around MFMA.

typedef short bf16x8 __attribute__((ext_vector_type(8)));
typedef float f32x4 __attribute__((ext_vector_type(4)));
typedef unsigned short us;

#define NB 32
#define NT_ 512
#define NS 1024
#define ND 1024

__device__ inline us f2bf(float x) {
  unsigned u = __float_as_uint(x);
  u += 0x7FFFu + ((u >> 16) & 1u);
  return (us)(u >> 16);
}
__device__ inline float bf2f(us h) { return __uint_as_float(((unsigned)h) << 16); }

__device__ inline void store_split(us* __restrict__ hi, us* __restrict__ lo, size_t idx, float v) {
  us h = f2bf(v);
  hi[idx] = h;
  lo[idx] = f2bf(v - bf2f(h));
}

// ---------------- elementwise split / convert ----------------
__global__ void ga_split(const float* __restrict__ src, us* __restrict__ hi,
                         us* __restrict__ lo, long n) {
  long i0 = ((long)blockIdx.x * blockDim.x + threadIdx.x) * 4;
  long stride = (long)gridDim.x * blockDim.x * 4;
  for (long i = i0; i < n; i += stride) {
    float4 v = *reinterpret_cast<const float4*>(src + i);
    ushort4 h, l;
    h.x = f2bf(v.x); l.x = f2bf(v.x - bf2f(h.x));
    h.y = f2bf(v.y); l.y = f2bf(v.y - bf2f(h.y));
    h.z = f2bf(v.z); l.z = f2bf(v.z - bf2f(h.z));
    h.w = f2bf(v.w); l.w = f2bf(v.w - bf2f(h.w));
    *reinterpret_cast<ushort4*>(hi + i) = h;
    *reinterpret_cast<ushort4*>(lo + i) = l;
  }
}

__global__ void ga_cvt(const float* __restrict__ src, us* __restrict__ dst, long n) {
  long i0 = ((long)blockIdx.x * blockDim.x + threadIdx.x) * 4;
  long stride = (long)gridDim.x * blockDim.x * 4;
  for (long i = i0; i < n; i += stride) {
    float4 v = *reinterpret_cast<const float4*>(src + i);
    ushort4 h;
    h.x = f2bf(v.x); h.y = f2bf(v.y); h.z = f2bf(v.z); h.w = f2bf(v.w);
    *reinterpret_cast<ushort4*>(dst + i) = h;
  }
}

// ---------------- ctx transpose+split: [B][S][D] f32 -> [B][D][S] bf16 hi/lo ----------------
__global__ void ga_transpose_split(const float* __restrict__ ctx, us* __restrict__ tHi,
                                   us* __restrict__ tLo) {
  __shared__ float tile[64][65];
  int s0 = blockIdx.x << 6, d0 = blockIdx.y << 6, b = blockIdx.z;
  const float* src = ctx + (size_t)b * NS * ND;
  int tid = threadIdx.x;
#pragma unroll
  for (int i = 0; i < 16; ++i) {
    int lin = (i << 8) + tid;
    int r = lin >> 6, c = lin & 63;
    tile[r][c] = src[(size_t)(s0 + r) * ND + d0 + c];
  }
  __syncthreads();
  us* oH = tHi + (size_t)b * ND * NS;
  us* oL = tLo + (size_t)b * ND * NS;
#pragma unroll
  for (int i = 0; i < 16; ++i) {
    int lin = (i << 8) + tid;
    int dr = lin >> 6, sc = lin & 63;
    float v = tile[sc][dr];
    size_t o = (size_t)(d0 + dr) * NS + s0 + sc;
    us h = f2bf(v);
    oH[o] = h;
    oL[o] = f2bf(v - bf2f(h));
  }
}

// ---------------- row softmax, in-place f32 + split planes ----------------
__global__ __launch_bounds__(256) void ga_softmax(float* __restrict__ al,
                                                  us* __restrict__ pHi, us* __restrict__ pLo) {
  int row = blockIdx.x;  // t*32 + b
  int tid = threadIdx.x;
  float* p = al + (size_t)row * NS;
  float4 v = *reinterpret_cast<const float4*>(p + (tid << 2));
  float m = fmaxf(fmaxf(v.x, v.y), fmaxf(v.z, v.w));
#pragma unroll
  for (int off = 32; off; off >>= 1) m = fmaxf(m, __shfl_xor(m, off));
  __shared__ float rmax[4], rsum[4];
  int wv = tid >> 6, ln = tid & 63;
  if (ln == 0) rmax[wv] = m;
  __syncthreads();
  m = fmaxf(fmaxf(rmax[0], rmax[1]), fmaxf(rmax[2], rmax[3]));
  float4 e;
  e.x = __expf(v.x - m); e.y = __expf(v.y - m);
  e.z = __expf(v.z - m); e.w = __expf(v.w - m);
  float s = e.x + e.y + e.z + e.w;
#pragma unroll
  for (int off = 32; off; off >>= 1) s += __shfl_xor(s, off);
  if (ln == 0) rsum[wv] = s;
  __syncthreads();
  s = rsum[0] + rsum[1] + rsum[2] + rsum[3];
  float inv = 1.0f / s;
  e.x *= inv; e.y *= inv; e.z *= inv; e.w *= inv;
  *reinterpret_cast<float4*>(p + (tid << 2)) = e;
  int t = row >> 5, b = row & 31;
  size_t o = ((size_t)b * NT_ + t) * NS + (tid << 2);
  ushort4 h, l;
  h.x = f2bf(e.x); l.x = f2bf(e.x - bf2f(h.x));
  h.y = f2bf(e.y); l.y = f2bf(e.y - bf2f(h.y));
  h.z = f2bf(e.z); l.z = f2bf(e.z - bf2f(h.z));
  h.w = f2bf(e.w); l.w = f2bf(e.w - bf2f(h.w));
  *reinterpret_cast<ushort4*>(pHi + o) = h;
  *reinterpret_cast<ushort4*>(pLo + o) = l;
}

// ---------------- 8-phase split-bf16 GEMM: C[M,N] = A[M,K] * B[N,K]^T ----------------
__device__ inline void gload16(const us* g, void* l) {
  __builtin_amdgcn_global_load_lds((const __attribute__((address_space(1))) unsigned int*)g,
                                   (__attribute__((address_space(3))) unsigned int*)l, 16, 0, 0);
}

__device__ inline f32x4 mfma16(bf16x8 a, bf16x8 b, f32x4 c) {
  return __builtin_amdgcn_mfma_f32_16x16x32_bf16(a, b, c, 0, 0, 0);
}

// LDS layout (bytes): buf b at b*65536. Planes: Ah +0, Al +16384, Bh +32768,
// Bl +49152 (16KB each). Within a plane: half q at q*8192; physical local row
// lr (0..127) at lr*64; 16B block blk holds source block blk ^ ((lr>>1)&3).
// A physical row: lr = (wr)*64 + (row&63)  [global row = wr*128 + q*64 + (row&63)]
// B physical row: lr = (wc)*32 + (row&31)  [global row = wc*64 + q*32 + (row&31)]
//
// Phase (qm,qn) reads A-half qm + B-half qn. Stage schedule per tile t:
//   ph0(0,0): stage (t+1).A1 -> buf cur^1
//   ph1(0,1): stage (t+1).B1 -> buf cur^1
//   ph2(1,0): stage (t+2).A0 -> buf cur   (A0 last read ph1)
//   ph3(1,1): stage (t+2).B0 -> buf cur   (B0 last read ph2); vmcnt(4|3); barrier
// vmcnt(4) leaves exactly (t+2).{A0,B0} in flight -> tile t+1 fully landed.

#define STAGE_A(tt, q) do {                                                        \
    const us *sah_, *sal_;                                                         \
    if constexpr (MODE == 3) {                                                     \
      if ((tt) < (NT >> 1)) { sah_ = pAh + (size_t)(tt) * 32;                      \
                              sal_ = pAl + (size_t)(tt) * 32; }                    \
      else { sah_ = pA2h + (size_t)((tt) - (NT >> 1)) * 32;                        \
             sal_ = pA2l + (size_t)((tt) - (NT >> 1)) * 32; }                      \
    } else { sah_ = pAh + (size_t)(tt) * 32; sal_ = pAl + (size_t)(tt) * 32; }     \
    long so_ = aoff0 + (long)(q) * 64 * lda;                                       \
    char* d_ = lb + (((tt) & 1) << 16) + ((q) << 13) + sdst;                       \
    gload16(sah_ + so_, d_);                                                       \
    gload16(sal_ + so_, d_ + 16384);                                               \
  } while (0)

#define STAGE_B(tt, q) do {                                                        \
    long so_ = boff0 + (long)(q) * 32 * ldb + (long)(tt) * 32;                     \
    char* d_ = lb + (((tt) & 1) << 16) + 32768 + ((q) << 13) + sdst;               \
    gload16(pBh + so_, d_);                                                        \
    if constexpr (MODE != 3) gload16(pBl + so_, d_ + 16384);                       \
  } while (0)

#define PHASE(QM, QN, STAGE, TAIL) do {                                            \
    const char* pA_ = lb + (cur << 16) + ((QM) << 13);                             \
    const char* pB_ = lb + (cur << 16) + 32768 + ((QN) << 13);                     \
    bf16x8 ah_[4], al_[4], bh_[2], bl_[2];                                         \
    _Pragma("unroll") for (int m = 0; m < 4; ++m) {                                \
      ah_[m] = *(const bf16x8*)(pA_ + arb + (m << 10));                            \
      al_[m] = *(const bf16x8*)(pA_ + 16384 + arb + (m << 10));                    \
    }                                                                              \
    _Pragma("unroll") for (int n = 0; n < 2; ++n) {                                \
      bh_[n] = *(const bf16x8*)(pB_ + brb + (n << 10));                            \
      if constexpr (MODE != 3)                                                     \
        bl_[n] = *(const bf16x8*)(pB_ + 16384 + brb + (n << 10));                  \
    }                                                                              \
    STAGE;                                                                         \
    __builtin_amdgcn_s_barrier();                                                  \
    __builtin_amdgcn_s_setprio(1);                                                 \
    _Pragma("unroll") for (int m = 0; m < 4; ++m)                                  \
    _Pragma("unroll") for (int n = 0; n < 2; ++n) {                                \
      f32x4& a_ = acc[(QM) * 4 + m][(QN) * 2 + n];                                 \
      a_ = mfma16(ah_[m], bh_[n], a_);                                             \
      if constexpr (MODE != 3) a_ = mfma16(ah_[m], bl_[n], a_);                    \
      a_ = mfma16(al_[m], bh_[n], a_);                                             \
    }                                                                              \
    __builtin_amdgcn_s_setprio(0);                                                 \
    TAIL;                                                                          \
    __builtin_amdgcn_s_barrier();                                                  \
  } while (0)

#define VM_STEADY do {                                                             \
    if constexpr (MODE == 3) asm volatile("s_waitcnt vmcnt(3)" ::: "memory");      \
    else asm volatile("s_waitcnt vmcnt(4)" ::: "memory");                          \
  } while (0)

// MODE 0: GEMM1 in*W_in^T -> h hi/lo planes.        grid(64,4,1)
// MODE 1: GEMM2 h*ctx^T   -> f32 align (t*32+b,s).  grid(2,4,32)
// MODE 2: GEMM3 P*ctxT^T  -> c hi/lo planes.        grid(2,4,32)
// MODE 3: GEMM4 concat[c,in]*W_out^T -> tanh f32.   grid(64,4,1), 2-term
template <int MODE>
__global__ __launch_bounds__(512, 2) void ga_gemm8(
    const us* __restrict__ Ahi, const us* __restrict__ Alo,
    const us* __restrict__ A2hi, const us* __restrict__ A2lo,
    const us* __restrict__ Bhi, const us* __restrict__ Blo,
    void* __restrict__ out0, void* __restrict__ out1,
    int K, int lda, int ldb, long astride, long bstride) {
  __shared__ __align__(16) char lds[131072];
  const int NT = K >> 5;
  const int tid = threadIdx.x;
  const int lane = tid & 63;
  const int wv = tid >> 6;
  const int wr = wv >> 2, wc = wv & 3;  // 2M x 4N wave grid
  const int fr = lane & 15;
  const int blk0 = lane >> 4;
  const int bx = blockIdx.x, by = blockIdx.y, bz = blockIdx.z;
  const int rowA = bx << 8, colB = by << 8;

  const us* pAh = Ahi + (size_t)bz * astride + (size_t)rowA * lda;
  const us* pAl = Alo + (size_t)bz * astride + (size_t)rowA * lda;
  const us* pA2h = (MODE == 3) ? A2hi + (size_t)rowA * lda : nullptr;
  const us* pA2l = (MODE == 3) ? A2lo + (size_t)rowA * lda : nullptr;
  const us* pBh = Bhi + (size_t)bz * bstride + (size_t)colB * ldb;
  const us* pBl = (MODE == 3) ? nullptr : Blo + (size_t)bz * bstride + (size_t)colB * ldb;

  // staging geometry: 1 chunk (16B) per thread per half-plane
  const int sprow = tid >> 2;                                  // physical local row
  const int sblkx = ((tid & 3) ^ ((sprow >> 1) & 3)) << 3;     // swizzled src col (elems)
  const long aoff0 = (long)((sprow >> 6) * 128 + (sprow & 63)) * lda + sblkx;
  const long boff0 = (long)((sprow >> 5) * 64 + (sprow & 31)) * ldb + sblkx;
  char* lb = lds;
  const int sdst = tid << 4;

  // frag read byte offsets within plane (swizzled)
  const int rdsw = (blk0 ^ ((fr >> 1) & 3)) << 4;
  const int arb = (wr << 12) + (fr << 6) + rdsw;
  const int brb = (wc << 11) + (fr << 6) + rdsw;

  f32x4 zero = {0.f, 0.f, 0.f, 0.f};
  f32x4 acc[8][4];
#pragma unroll
  for (int i = 0; i < 8; ++i)
#pragma unroll
    for (int k = 0; k < 4; ++k) acc[i][k] = zero;

  // prologue: tile0 full + tile1.{A0,B0}; wait tile0 landed
  STAGE_A(0, 0); STAGE_B(0, 0); STAGE_A(0, 1); STAGE_B(0, 1);
  STAGE_A(1, 0); STAGE_B(1, 0);
  VM_STEADY;
  __builtin_amdgcn_s_barrier();

  int cur = 0;
  for (int t = 0; t < NT; ++t) {
    const bool s1 = (t + 1 < NT), s2 = (t + 2 < NT);
    PHASE(0, 0, { if (s1) STAGE_A(t + 1, 1); }, {});
    PHASE(0, 1, { if (s1) STAGE_B(t + 1, 1); }, {});
    PHASE(1, 0, { if (s2) STAGE_A(t + 2, 0); }, {});
    PHASE(1, 1, { if (s2) STAGE_B(t + 2, 0); },
          { if (s1) { if (s2) { VM_STEADY; }
                      else { asm volatile("s_waitcnt vmcnt(0)" ::: "memory"); } } });
    cur ^= 1;
  }

  // epilogue
#pragma unroll
  for (int i = 0; i < 8; ++i)
#pragma unroll
    for (int k = 0; k < 4; ++k)
#pragma unroll
      for (int j = 0; j < 4; ++j) {
        int r = rowA + (wr << 7) + ((i >> 2) << 6) + ((i & 3) << 4) + ((lane >> 4) << 2) + j;
        int c = colB + (wc << 6) + ((k >> 1) << 5) + ((k & 1) << 4) + fr;
        float v = acc[i][k][j];
        if constexpr (MODE == 0) {
          store_split((us*)out0, (us*)out1, (size_t)r * 1024 + c, v);
        } else if constexpr (MODE == 1) {
          ((float*)out0)[((size_t)r * NB + bz) * NS + c] = v;  // align[t][b][s]
        } else if constexpr (MODE == 2) {
          store_split((us*)out0, (us*)out1, ((size_t)bz * 512 + r) * 1024 + c, v);
        } else {
          int bb = r >> 9, tt2 = r & 511;
          ((float*)out0)[((size_t)tt2 * NB + bb) * ND + c] = tanhf(v);  // attn[t][b][d]
        }
      }
}

// ---------------- launch ----------------
extern "C" void kernel_launch(void* const* d_in, const int* in_sizes, int n_in,
                              void* d_out, int out_size, void* d_ws, size_t ws_size,
                              hipStream_t stream) {
  (void)in_sizes; (void)n_in; (void)out_size; (void)ws_size;
  const float* inp = (const float*)d_in[0];   // [32][512][1024]
  const float* ctx = (const float*)d_in[1];   // [32][1024][1024]
  const float* Win = (const float*)d_in[2];   // [1024][1024] (e,d)
  const float* Wout = (const float*)d_in[3];  // [1024][2048] (d,f)
  float* out = (float*)d_out;

  char* w = (char*)d_ws;
  us* ctx_hi  = (us*)(w + 0);
  us* c_hi    = (us*)(w + 0);
  us* c_lo    = (us*)(w + 33554432);
  us* ctx_lo  = (us*)(w + 67108864);
  us* p_hi    = (us*)(w + 67108864);
  us* p_lo    = (us*)(w + 100663296);
  us* in_hi   = (us*)(w + 134217728);
  us* in_lo   = (us*)(w + 167772160);
  us* h_hi    = (us*)(w + 201326592);
  us* h_lo    = (us*)(w + 234881024);
  us* ctxT_lo = (us*)(w + 201326592);  // reuses h region after GEMM2
  us* win_hi  = (us*)(w + 268435456);
  us* win_lo  = (us*)(w + 270532608);
  us* wout_b  = (us*)(w + 272629760);

  us* ctxT_hi = (us*)d_out;            // attn region as scratch until GEMM4
  float* alignOut = out + 16777216;    // second half of d_out

  ga_split<<<2048, 256, 0, stream>>>(inp, in_hi, in_lo, 16777216L);
  ga_split<<<2048, 256, 0, stream>>>(ctx, ctx_hi, ctx_lo, 33554432L);
  ga_split<<<512, 256, 0, stream>>>(Win, win_hi, win_lo, 1048576L);
  ga_cvt<<<512, 256, 0, stream>>>(Wout, wout_b, 2097152L);

  // GEMM1: h = in @ W_in^T   (M=16384, N=1024, K=1024)
  ga_gemm8<0><<<dim3(64, 4, 1), 512, 0, stream>>>(in_hi, in_lo, nullptr, nullptr,
                                                  win_hi, win_lo, h_hi, h_lo,
                                                  1024, 1024, 1024, 0L, 0L);
  // GEMM2: align = h @ ctx^T (batched over 32; M=512, N=1024, K=1024)
  ga_gemm8<1><<<dim3(2, 4, 32), 512, 0, stream>>>(h_hi, h_lo, nullptr, nullptr,
                                                  ctx_hi, ctx_lo, alignOut, nullptr,
                                                  1024, 1024, 1024, 524288L, 1048576L);
  // ctx transpose+split (overwrites h region -> must follow GEMM2; stream-ordered)
  ga_transpose_split<<<dim3(16, 16, 32), 256, 0, stream>>>(ctx, ctxT_hi, ctxT_lo);
  // softmax in-place + P split planes
  ga_softmax<<<16384, 256, 0, stream>>>(alignOut, p_hi, p_lo);
  // GEMM3: c = P @ ctx (via ctxT planes; batched; M=512, N=1024, K=1024)
  ga_gemm8<2><<<dim3(2, 4, 32), 512, 0, stream>>>(p_hi, p_lo, nullptr, nullptr,
                                                  ctxT_hi, ctxT_lo, c_hi, c_lo,
                                                  1024, 1024, 1024, 524288L, 1048576L);
  // GEMM4: attn = tanh(concat[c,in] @ W_out^T) (M=16384, N=1024, K=2048, 2-term)
  ga_gemm8<3><<<dim3(64, 4, 1), 512, 0, stream>>>(c_hi, c_lo, in_hi, in_lo,
                                                  wout_b, nullptr, out, nullptr,
                                                  2048, 1024, 2048, 0L, 0L);
}